// Round 1
// baseline (782.682 us; speedup 1.0000x reference)
//
#include <hip/hip_runtime.h>
#include <hip/hip_bf16.h>
#include <math.h>

// Problem constants (from reference file)
#define BB 16
#define LL 3136
#define CC 96
#define HH 56
#define WW 56
#define RR 3
#define RTOT 5
#define EE 131072
#define NR (BB*LL)            // 50176 rows
#define NSEG (LL*RR)          // 9408 segments
#define FFN 384

// ---------------- LayerNorm: one wave per row (96 elems) ----------------
__global__ __launch_bounds__(256) void ln_kernel(const float* __restrict__ x,
                                                 const float* __restrict__ g,
                                                 const float* __restrict__ bta,
                                                 float* __restrict__ out, int nrows)
{
    int wave = threadIdx.x >> 6;
    int lane = threadIdx.x & 63;
    int row  = blockIdx.x * 4 + wave;
    if (row >= nrows) return;
    const float* xr = x + (size_t)row * CC;
    float v0 = xr[lane];
    float v1 = (lane < 32) ? xr[64 + lane] : 0.f;
    float s = v0 + v1;
    #pragma unroll
    for (int off = 32; off; off >>= 1) s += __shfl_xor(s, off);
    float mean = s * (1.f / 96.f);
    float d0 = v0 - mean;
    float d1 = (lane < 32) ? (v1 - mean) : 0.f;
    float q = d0 * d0 + d1 * d1;
    #pragma unroll
    for (int off = 32; off; off >>= 1) q += __shfl_xor(q, off);
    float rstd = rsqrtf(q * (1.f / 96.f) + 1e-5f);
    out[(size_t)row * CC + lane] = d0 * rstd * g[lane] + bta[lane];
    if (lane < 32)
        out[(size_t)row * CC + 64 + lane] = d1 * rstd * g[64 + lane] + bta[64 + lane];
}

// ---------------- Generic tiled fp32 GEMM: out = act(A@B + bias) (+res) ----------------
// BM=64, BN=96, BK=16, 256 threads, 4x6 microtile.
__device__ __forceinline__ float gelu_exact(float v) {
    return 0.5f * v * (1.0f + erff(v * 0.70710678118654752440f));
}

template<int ACT, bool RES>
__global__ __launch_bounds__(256) void gemm_kernel(const float* __restrict__ A,
                                                   const float* __restrict__ Bm,
                                                   const float* __restrict__ bias,
                                                   const float* __restrict__ res,
                                                   float* __restrict__ out,
                                                   int M, int N, int K)
{
    const int BM = 64, BN = 96, BK = 16, TN = 6;
    __shared__ float As[BK][BM];   // transposed A tile
    __shared__ float Bs[BK][BN];
    int bm = blockIdx.x * BM;
    int bn = blockIdx.y * BN;
    int tid = threadIdx.x;
    int tx = tid & 15;   // n direction
    int ty = tid >> 4;   // m direction
    float acc[4][TN];
    #pragma unroll
    for (int i = 0; i < 4; i++)
        #pragma unroll
        for (int j = 0; j < TN; j++) acc[i][j] = 0.f;

    for (int k0 = 0; k0 < K; k0 += BK) {
        // A tile: 64 rows x 16 k, float4 per thread
        {
            int r = tid >> 2;
            int c = (tid & 3) << 2;
            const float* ap = A + (size_t)(bm + r) * K + k0 + c;
            float4 a4 = *(const float4*)ap;
            As[c + 0][r] = a4.x; As[c + 1][r] = a4.y;
            As[c + 2][r] = a4.z; As[c + 3][r] = a4.w;
        }
        // B tile: 16 x 96
        #pragma unroll
        for (int e = tid; e < BK * BN; e += 256) {
            int r = e / BN; int c = e - r * BN;
            Bs[r][c] = Bm[(size_t)(k0 + r) * N + bn + c];
        }
        __syncthreads();
        #pragma unroll
        for (int kk = 0; kk < BK; ++kk) {
            float a[4], b[TN];
            #pragma unroll
            for (int i = 0; i < 4; i++) a[i] = As[kk][ty * 4 + i];
            #pragma unroll
            for (int j = 0; j < TN; j++) b[j] = Bs[kk][tx * TN + j];
            #pragma unroll
            for (int i = 0; i < 4; i++)
                #pragma unroll
                for (int j = 0; j < TN; j++)
                    acc[i][j] += a[i] * b[j];
        }
        __syncthreads();
    }
    #pragma unroll
    for (int i = 0; i < 4; i++) {
        int row = bm + ty * 4 + i;
        #pragma unroll
        for (int j = 0; j < TN; j++) {
            int col = bn + tx * TN + j;
            float val = acc[i][j] + bias[col];
            if (ACT == 1) val = gelu_exact(val);
            if (RES) val += res[(size_t)row * N + col];
            out[(size_t)row * N + col] = val;
        }
    }
}

// ---------------- Gate: sigmoid(h @ gate_w + gate_b), thread per (row, r) ----------------
__global__ void gate_kernel(const float* __restrict__ h, const float* __restrict__ gw,
                            const float* __restrict__ gb, float* __restrict__ gate)
{
    int t = blockIdx.x * 256 + threadIdx.x;
    if (t >= NR * RTOT) return;
    int row = t / RTOT, r = t - row * RTOT;
    const float* hr = h + (size_t)row * CC;
    float acc = gb[r];
    #pragma unroll 4
    for (int k = 0; k < CC; k++) acc += hr[k] * gw[k * RTOT + r];
    gate[t] = 1.f / (1.f + expf(-acc));
}

// ---------------- CSR build ----------------
__global__ void hist_kernel(const int* __restrict__ ei, const int* __restrict__ et,
                            int* __restrict__ cnt)
{
    int e = blockIdx.x * 256 + threadIdx.x;
    if (e >= EE) return;
    int dst = ei[EE + e];
    int r   = et[e];
    atomicAdd(&cnt[dst * RR + r], 1);
}

__global__ void scan_kernel(const int* __restrict__ cnt, int* __restrict__ colptr,
                            float* __restrict__ invcnt)
{
    int lane = threadIdx.x;  // 64 threads, NSEG % 64 == 0
    int carry = 0;
    for (int base = 0; base < NSEG; base += 64) {
        int vi = cnt[base + lane];
        invcnt[base + lane] = 1.f / (float)max(vi, 1);
        int sc = vi;
        #pragma unroll
        for (int off = 1; off < 64; off <<= 1) {
            int o = __shfl_up(sc, off);
            if (lane >= off) sc += o;
        }
        colptr[base + lane] = carry + sc - vi;   // exclusive
        carry += __shfl(sc, 63);
    }
    if (lane == 0) colptr[NSEG] = carry;
}

__global__ void scatter_kernel(const int* __restrict__ ei, const int* __restrict__ et,
                               const int* __restrict__ colptr, int* __restrict__ fill,
                               int* __restrict__ esorted)
{
    int e = blockIdx.x * 256 + threadIdx.x;
    if (e >= EE) return;
    int src = ei[e];
    int dst = ei[EE + e];
    int seg = dst * RR + et[e];
    int pos = colptr[seg] + atomicAdd(&fill[seg], 1);
    esorted[pos] = src;
}

// ---------------- Aggregation + depthwise convs + gating → updg [B,L,480] ----------------
__global__ void aggconv_kernel(const float* __restrict__ v, const float* __restrict__ gate,
                               const int* __restrict__ colptr, const int* __restrict__ esorted,
                               const float* __restrict__ invcnt,
                               const float* __restrict__ k3, const float* __restrict__ b3,
                               const float* __restrict__ k5, const float* __restrict__ b5,
                               float* __restrict__ updg)
{
    int l = blockIdx.x;      // spatial index
    int b = blockIdx.y;      // batch
    int c = threadIdx.x;     // channel 0..95
    __shared__ float gs[RTOT];
    if (c < RTOT) gs[c] = gate[((size_t)b * LL + l) * RTOT + c];
    __syncthreads();
    const float* vb = v + (size_t)b * LL * CC;
    size_t outbase = ((size_t)b * LL + l) * (RTOT * CC);

    #pragma unroll
    for (int r = 0; r < RR; r++) {
        int s0 = colptr[l * RR + r], s1 = colptr[l * RR + r + 1];
        float s = 0.f;
        for (int e = s0; e < s1; e++) {
            int src = esorted[e];
            s += vb[(size_t)src * CC + c];
        }
        updg[outbase + r * CC + c] = s * invcnt[l * RR + r] * gs[r];
    }

    int h0 = l / WW, w0 = l - (l / WW) * WW;
    // 3x3 depthwise
    float s3 = b3[c];
    #pragma unroll
    for (int kh = -1; kh <= 1; kh++) {
        int hh = h0 + kh; if (hh < 0 || hh >= HH) continue;
        #pragma unroll
        for (int kw = -1; kw <= 1; kw++) {
            int ww = w0 + kw; if (ww < 0 || ww >= WW) continue;
            s3 += vb[((size_t)(hh * WW + ww)) * CC + c] * k3[c * 9 + (kh + 1) * 3 + (kw + 1)];
        }
    }
    updg[outbase + 3 * CC + c] = s3 * gs[3];
    // 5x5 depthwise
    float s5 = b5[c];
    #pragma unroll
    for (int kh = -2; kh <= 2; kh++) {
        int hh = h0 + kh; if (hh < 0 || hh >= HH) continue;
        #pragma unroll
        for (int kw = -2; kw <= 2; kw++) {
            int ww = w0 + kw; if (ww < 0 || ww >= WW) continue;
            s5 += vb[((size_t)(hh * WW + ww)) * CC + c] * k5[c * 25 + (kh + 2) * 5 + (kw + 2)];
        }
    }
    updg[outbase + 4 * CC + c] = s5 * gs[4];
}

// ---------------- launch ----------------
extern "C" void kernel_launch(void* const* d_in, const int* in_sizes, int n_in,
                              void* d_out, int out_size, void* d_ws, size_t ws_size,
                              hipStream_t stream)
{
    const float* x       = (const float*)d_in[0];
    const int*   ei      = (const int*)d_in[1];
    const int*   et      = (const int*)d_in[2];
    // d_in[3], d_in[4] = H, W (hardcoded 56)
    const float* n1g     = (const float*)d_in[5];
    const float* n1b     = (const float*)d_in[6];
    const float* value_w = (const float*)d_in[7];
    const float* value_b = (const float*)d_in[8];
    const float* gate_w  = (const float*)d_in[9];
    const float* gate_b  = (const float*)d_in[10];
    const float* k3      = (const float*)d_in[11];
    const float* b3      = (const float*)d_in[12];
    const float* k5      = (const float*)d_in[13];
    const float* b5      = (const float*)d_in[14];
    const float* rel_w   = (const float*)d_in[15];
    const float* rel_b   = (const float*)d_in[16];
    const float* proj_w  = (const float*)d_in[17];
    const float* proj_b  = (const float*)d_in[18];
    const float* n2g     = (const float*)d_in[19];
    const float* n2b     = (const float*)d_in[20];
    const float* fc1_w   = (const float*)d_in[21];
    const float* fc1_b   = (const float*)d_in[22];
    const float* fc2_w   = (const float*)d_in[23];
    const float* fc2_b   = (const float*)d_in[24];
    float* out = (float*)d_out;

    // workspace layout (floats)
    float* w = (float*)d_ws;
    const size_t SZ_ROW = (size_t)NR * CC;            // 4,816,896
    float* hbuf   = w;                                 // h, later g1, later h2
    float* vbuf   = hbuf + SZ_ROW;                     // v, later x1
    float* gateb  = vbuf + SZ_ROW;                     // [NR,5]
    float* updg   = gateb + (size_t)NR * RTOT;         // [NR,480], later ffn hidden [NR,384]
    int*   ibase  = (int*)(updg + (size_t)NR * RTOT * CC);
    int*   cnt     = ibase;                            // [NSEG]
    int*   colptr  = cnt + NSEG;                       // [NSEG+1]
    int*   fill    = colptr + NSEG + 1;                // [NSEG]
    int*   esorted = fill + NSEG;                      // [E]
    float* invcnt  = (float*)(esorted + EE);           // [NSEG]

    // zero the counters
    hipMemsetAsync(cnt, 0, NSEG * sizeof(int), stream);
    hipMemsetAsync(fill, 0, NSEG * sizeof(int), stream);

    // 1. LN1
    ln_kernel<<<(NR + 3) / 4, 256, 0, stream>>>(x, n1g, n1b, hbuf, NR);
    // 2. v = h @ value_w + value_b
    gemm_kernel<0, false><<<dim3(NR / 64, 1), 256, 0, stream>>>(hbuf, value_w, value_b, nullptr, vbuf, NR, CC, CC);
    // 3. gates
    gate_kernel<<<(NR * RTOT + 255) / 256, 256, 0, stream>>>(hbuf, gate_w, gate_b, gateb);
    // 4. CSR build
    hist_kernel<<<EE / 256, 256, 0, stream>>>(ei, et, cnt);
    scan_kernel<<<1, 64, 0, stream>>>(cnt, colptr, invcnt);
    scatter_kernel<<<EE / 256, 256, 0, stream>>>(ei, et, colptr, fill, esorted);
    // 5. aggregation + convs + gating
    aggconv_kernel<<<dim3(LL, BB), CC, 0, stream>>>(vbuf, gateb, colptr, esorted, invcnt,
                                                    k3, b3, k5, b5, updg);
    // 6. g1 = gelu(updg @ rel_w + rel_b)  (into hbuf)
    gemm_kernel<1, false><<<dim3(NR / 64, 1), 256, 0, stream>>>(updg, rel_w, rel_b, nullptr, hbuf, NR, CC, RTOT * CC);
    // 7. x1 = x + g1 @ proj_w + proj_b   (into vbuf)
    gemm_kernel<0, true><<<dim3(NR / 64, 1), 256, 0, stream>>>(hbuf, proj_w, proj_b, x, vbuf, NR, CC, CC);
    // 8. h2 = LN2(x1)  (into hbuf)
    ln_kernel<<<(NR + 3) / 4, 256, 0, stream>>>(vbuf, n2g, n2b, hbuf, NR);
    // 9. hid = gelu(h2 @ fc1_w + fc1_b)  (into updg buffer)
    gemm_kernel<1, false><<<dim3(NR / 64, FFN / 96), 256, 0, stream>>>(hbuf, fc1_w, fc1_b, nullptr, updg, NR, FFN, CC);
    // 10. out = x1 + hid @ fc2_w + fc2_b
    gemm_kernel<0, true><<<dim3(NR / 64, 1), 256, 0, stream>>>(updg, fc2_w, fc2_b, vbuf, out, NR, CC, FFN);
}